// Round 16
// baseline (283.543 us; speedup 1.0000x reference)
//
#include <hip/hip_runtime.h>
#include <math.h>

typedef float f32x4 __attribute__((ext_vector_type(4)));
typedef short short8 __attribute__((ext_vector_type(8)));
typedef unsigned short u16;

#define LN_EPS 1e-5f

static __device__ __forceinline__ unsigned cvt_pk_bf16(float lo, float hi) {
    unsigned r;
    asm("v_cvt_pk_bf16_f32 %0, %1, %2" : "=v"(r) : "v"(lo), "v"(hi));
    return r;
}
static __device__ __forceinline__ u16 f2bf(float f) { return (u16)cvt_pk_bf16(f, f); }
static __device__ __forceinline__ float bf2f(u16 u) {
    return __uint_as_float(((unsigned)u) << 16);
}

// ws segment offsets (u16 elements). Fragment-linear layout (works as A- or B-operand):
// idx = ((ntile*Ksteps + kk)*64 + lane)*8 + j -> W[kk*32+(lane>>4)*8+j][ntile*16+(lane&15)]
#define OFF_QKV 0
#define OFF_WO  49152
#define OFF_WP  65536
#define OFF_PV  98304
#define OFF_PM  106496
#define OFF_PI  114688
#define OFF_PB  118784
#define OFF_PC  122880
#define OFF_PF  131072
#define OFF_WENC 147456     // block-diag encoder weight, hi/lo stacked: 24 ntiles x 2 ksteps
#define OFF_BENC 172032     // f32 region (384 floats) starts at this u16 index
#define CW_TOTAL 172416

__global__ __launch_bounds__(512) void convert_weights(
    const float* __restrict__ Wqkv, const float* __restrict__ Wo, const float* __restrict__ Wp,
    const float* __restrict__ Pv, const float* __restrict__ Pm, const float* __restrict__ Pi,
    const float* __restrict__ Pb, const float* __restrict__ Pc, const float* __restrict__ Pf,
    const float* __restrict__ Wv, const float* __restrict__ Wm, const float* __restrict__ Wi,
    const float* __restrict__ Wb, const float* __restrict__ Wc, const float* __restrict__ Wf,
    const float* __restrict__ bv, const float* __restrict__ bm, const float* __restrict__ bi,
    const float* __restrict__ bb, const float* __restrict__ bc, const float* __restrict__ bf_,
    u16* __restrict__ ws)
{
    int gid = blockIdx.x * 512 + threadIdx.x;
    if (gid < OFF_WENC) {
        const float* src; int N, Ksteps, local;
        if (gid < OFF_WO)      { src = Wqkv; N = 384; Ksteps = 4; local = gid; }
        else if (gid < OFF_WP) { src = Wo;   N = 128; Ksteps = 4; local = gid - OFF_WO; }
        else if (gid < OFF_PV) { src = Wp;   N = 256; Ksteps = 4; local = gid - OFF_WP; }
        else if (gid < OFF_PM) { src = Pv;   N = 128; Ksteps = 2; local = gid - OFF_PV; }
        else if (gid < OFF_PI) { src = Pm;   N = 128; Ksteps = 2; local = gid - OFF_PM; }
        else if (gid < OFF_PB) { src = Pi;   N = 128; Ksteps = 1; local = gid - OFF_PI; }
        else if (gid < OFF_PC) { src = Pb;   N = 128; Ksteps = 1; local = gid - OFF_PB; }
        else if (gid < OFF_PF) { src = Pc;   N = 128; Ksteps = 2; local = gid - OFF_PC; }
        else                   { src = Pf;   N = 128; Ksteps = 4; local = gid - OFF_PF; }
        int j  = local & 7;
        int l  = (local >> 3) & 63;
        int r2 = local >> 9;
        int kk = r2 % Ksteps;
        int nt = r2 / Ksteps;
        int srow = kk * 32 + (l >> 4) * 8 + j;
        int scol = nt * 16 + (l & 15);
        ws[gid] = f2bf(src[srow * N + scol]);
    } else if (gid < OFF_BENC) {
        int local = gid - OFF_WENC;
        int j = local & 7, l = (local >> 3) & 63, r2 = local >> 9;
        int kk = r2 & 1, nt = r2 >> 1;
        int k = kk * 32 + (l >> 4) * 8 + j;
        int r = k & 31;                    // x input dim (0..31, valid <29)
        int scol = nt * 16 + (l & 15);     // 0..383
        const float* W; int cb, xo, din, dout;
        if (scol < 64)       { W = Wv; cb = 0;   xo = 0;  din = 3;  dout = 64; }
        else if (scol < 128) { W = Wm; cb = 64;  xo = 3;  din = 5;  dout = 64; }
        else if (scol < 160) { W = Wi; cb = 128; xo = 8;  din = 2;  dout = 32; }
        else if (scol < 192) { W = Wb; cb = 160; xo = 10; din = 3;  dout = 32; }
        else if (scol < 256) { W = Wc; cb = 192; xo = 13; din = 6;  dout = 64; }
        else                 { W = Wf; cb = 256; xo = 19; din = 10; dout = 128; }
        int rr = r - xo;
        float val = (r < 29 && rr >= 0 && rr < din) ? W[rr * dout + (scol - cb)] : 0.f;
        ws[gid] = f2bf(val);
    } else if (gid < CW_TOTAL) {
        int j = gid - OFF_BENC;
        const float* b; int off;
        if (j < 64)       { b = bv;  off = 0; }
        else if (j < 128) { b = bm;  off = 64; }
        else if (j < 160) { b = bi;  off = 128; }
        else if (j < 192) { b = bb;  off = 160; }
        else if (j < 256) { b = bc;  off = 192; }
        else              { b = bf_; off = 256; }
        ((float*)(ws + OFF_BENC))[j] = b[j - off];
    }
}

// 8 rows/block, 48 tokens (token = comp*8 + row), 512 threads = 8 waves (wave = row).
// r15 (validated, 277.7 us) + s_setprio(1) around MFMA clusters (T5: arbitrates
// the matrix pipe between the 2 independent resident blocks; zero semantic effect).
__global__ __launch_bounds__(512, 4) void asmlp_mfma(
    const float* __restrict__ x,
    const float* __restrict__ pv, const float* __restrict__ pm,
    const float* __restrict__ pi_, const float* __restrict__ pb_,
    const float* __restrict__ pc_, const float* __restrict__ pf_,
    const float* __restrict__ bqkv, const float* __restrict__ bo,
    const float* __restrict__ gg, const float* __restrict__ beta,
    const float* __restrict__ bp,
    const u16* __restrict__ ws,
    float* __restrict__ out)
{
    const int blk  = blockIdx.x;
    const int t    = threadIdx.x;
    const int lane = t & 63;
    const int wv   = t >> 6;
    const int col  = lane & 15;
    const int lg   = lane >> 4;

    __shared__ __attribute__((aligned(16))) u16 sm[24576];   // 49152 B
    u16*   s_tok  = sm;                      // [48 tok][16 g][8] swz g^(tok&15)      12288 B
    u16*   s_vt   = sm + 6144;               // [16 g2][2 ch][16 nn][12 k=p*6+c2]     12288 B
    u16*   s_qk   = sm + 12288;              // col-major [256 col][48 tok]           24576 B
    u16*   s_xa   = sm + 12288;              // [8 row][64 k] hi/lo (overlay qk, S0-S2)
    u16*   s_h    = sm + 12800;              // [8 row][48 g][8] (overlay qk, S1-S2)
    u16*   s_ctx  = sm + 12288;              // [48 tok][16 g][8] (overlay qk, after scores)
    u16*   s_pp   = sm + 18432;              // [8 wv][2 slot][16 k][16 m] (overlay qk upper)
    float* s_part = (float*)(sm + 18432);    // [48 tok][8 wv][2] f32 (overlay pp; S6)
    u16*   s_pool = sm + 6144;               // [8 row][16 g][8] (overlay vt; S7+)

    // ---- S0: stage x as hi/lo bf16 (exact fp32 split), granule-swizzled ----
    if (t < 232) {
        int row = t / 29, cc = t - row * 29;
        float f = x[(size_t)blk * 232 + t];
        u16 hi = f2bf(f);
        float lo = f - bf2f(hi);
        s_xa[row * 64 + (((cc >> 3) ^ (row & 3)) << 3) + (cc & 7)] = hi;
        int c2 = cc + 32;
        s_xa[row * 64 + (((c2 >> 3) ^ (row & 3)) << 3) + (c2 & 7)] = f2bf(lo);
    }
    if (t < 48) {
        int row = t / 6, sl = t - (t / 6) * 6;
        int k = (sl < 3) ? (29 + sl) : (58 + sl);   // 29..31, 61..63
        s_xa[row * 64 + (((k >> 3) ^ (row & 3)) << 3) + (k & 7)] = 0;
    }
    __syncthreads();

    // ---- S1: encoders, transposed MFMA: C[enc_col][row] ----
    {
        int row8 = col & 7;
        short8 B0 = *(const short8*)&s_xa[row8 * 64 + ((lg ^ (row8 & 3)) << 3)];
        short8 B1 = *(const short8*)&s_xa[row8 * 64 + (((4 + lg) ^ (row8 & 3)) << 3)];
        const float* benc = (const float*)(ws + OFF_BENC);
        #pragma unroll
        for (int q = 0; q < 3; ++q) {
            int nt = wv * 3 + q;
            f32x4 acc = *(const f32x4*)&benc[nt * 16 + lg * 4];
            short8 A0 = *(const short8*)&ws[OFF_WENC + (((nt * 2 + 0) * 64 + lane) << 3)];
            short8 A1 = *(const short8*)&ws[OFF_WENC + (((nt * 2 + 1) * 64 + lane) << 3)];
            __builtin_amdgcn_s_setprio(1);
            acc = __builtin_amdgcn_mfma_f32_16x16x32_bf16(A0, B0, acc, 0, 0, 0);
            acc = __builtin_amdgcn_mfma_f32_16x16x32_bf16(A1, B1, acc, 0, 0, 0);
            __builtin_amdgcn_s_setprio(0);
            if (col < 8) {
                int ge = nt * 2 + (lg >> 1);
                uint2 w;
                w.x = cvt_pk_bf16(fmaxf(acc[0], 0.f), fmaxf(acc[1], 0.f));
                w.y = cvt_pk_bf16(fmaxf(acc[2], 0.f), fmaxf(acc[3], 0.f));
                *(uint2*)&s_h[((col * 48 + (ge ^ col)) << 3) + (lg & 1) * 4] = w;
            }
        }
    }
    __syncthreads();

    // ---- S2: projections, transposed: C[proj_col][row] ----
    #pragma unroll
    for (int q = 0; q < 6; ++q) {
        int unit = wv * 6 + q;
        int c = unit >> 3, n = unit & 7;
        const float* bias; int ks, hg, wso;
        switch (c) {
            case 0:  bias = pv;  ks = 2; hg = 0;  wso = OFF_PV; break;
            case 1:  bias = pm;  ks = 2; hg = 8;  wso = OFF_PM; break;
            case 2:  bias = pi_; ks = 1; hg = 16; wso = OFF_PI; break;
            case 3:  bias = pb_; ks = 1; hg = 20; wso = OFF_PB; break;
            case 4:  bias = pc_; ks = 2; hg = 24; wso = OFF_PC; break;
            default: bias = pf_; ks = 4; hg = 32; wso = OFF_PF; break;
        }
        f32x4 acc = *(const f32x4*)&bias[n * 16 + lg * 4];
        int hrow = col & 7;
        for (int kk = 0; kk < ks; ++kk) {
            short8 A = *(const short8*)&ws[wso + (((n * ks + kk) * 64 + lane) << 3)];
            short8 B = *(const short8*)&s_h[(hrow * 48 + ((hg + kk * 4 + lg) ^ hrow)) << 3];
            __builtin_amdgcn_s_setprio(1);
            acc = __builtin_amdgcn_mfma_f32_16x16x32_bf16(A, B, acc, 0, 0, 0);
            __builtin_amdgcn_s_setprio(0);
        }
        if (col < 8) {
            int tok = c * 8 + col;
            int gt = n * 2 + (lg >> 1);
            uint2 w;
            w.x = cvt_pk_bf16(acc[0], acc[1]);
            w.y = cvt_pk_bf16(acc[2], acc[3]);
            *(uint2*)&s_tok[((tok * 16 + (gt ^ (tok & 15))) << 3) + (lg & 1) * 4] = w;
        }
    }
    __syncthreads();

    // ---- S3: QKV (MFMA). Q/K -> col-major s_qk (cvt_pk + b64); V -> s_vt [*12] ----
    {
        short8 Bf[3][4];
        float  bb_[3];
        #pragma unroll
        for (int ni = 0; ni < 3; ++ni) {
            int n = wv * 3 + ni;
            bb_[ni] = bqkv[n * 16 + col];
            #pragma unroll
            for (int kk = 0; kk < 4; ++kk)
                Bf[ni][kk] = *(const short8*)&ws[OFF_QKV + (((n * 4 + kk) * 64 + lane) << 3)];
        }
        for (int mt = 0; mt < 3; ++mt) {
            short8 A[4];
            int arow = mt * 16 + col;
            #pragma unroll
            for (int kk = 0; kk < 4; ++kk) {
                int g = kk * 4 + lg;
                A[kk] = *(const short8*)&s_tok[(arow * 16 + (g ^ (arow & 15))) << 3];
            }
            #pragma unroll
            for (int ni = 0; ni < 3; ++ni) {
                f32x4 acc = {bb_[ni], bb_[ni], bb_[ni], bb_[ni]};
                __builtin_amdgcn_s_setprio(1);
                #pragma unroll
                for (int kk = 0; kk < 4; ++kk)
                    acc = __builtin_amdgcn_mfma_f32_16x16x32_bf16(A[kk], Bf[ni][kk], acc, 0, 0, 0);
                __builtin_amdgcn_s_setprio(0);
                int cn = wv * 3 + ni;
                int cg = cn * 16 + col;                 // global qkv column
                if (cn < 16) {
                    // Q/K: col-major, token index XOR-swizzled by ((cg>>3)&3)<<2
                    int q4 = ((cg >> 3) & 3) << 2;
                    int tb = (mt * 16 + lg * 4) ^ q4;
                    uint2 w;
                    w.x = cvt_pk_bf16(acc[0], acc[1]);
                    w.y = cvt_pk_bf16(acc[2], acc[3]);
                    *(uint2*)&s_qk[cg * 48 + tb] = w;
                } else {
                    int d = cg - 256;
                    int h = d >> 5, ch = (d >> 4) & 1, nn = d & 15;
                    #pragma unroll
                    for (int r = 0; r < 4; ++r) {
                        int token = mt * 16 + lg * 4 + r;
                        int c2 = token >> 3, rb = token & 7;
                        int g2 = rb * 2 + (h >> 1);
                        int kidx = (h & 1) * 6 + c2;
                        s_vt[((g2 * 2 + ch) * 16 + nn) * 12 + kidx] = f2bf(acc[r]);
                    }
                }
            }
        }
    }
    __syncthreads();

    // ---- SCORES phase 1: MFMAs only (last readers of s_qk) ----
    f32x4 scf[2];
    {
        const int rb = wv;
        #pragma unroll
        for (int i = 0; i < 2; ++i) {
            const int hp = i;
            int p  = (col >= 6 && col < 12) ? 1 : 0;
            int qi = (col < 6) ? col : ((col < 12) ? col - 6 : 0);
            int tt = qi * 8 + rb;
            int h  = hp * 2 + p;
            int tsw = tt ^ (lg << 2);
            int abase = (h * 32 + lg * 8) * 48 + tsw;          // Q cols 0..127
            int bbase = (128 + h * 32 + lg * 8) * 48 + tsw;    // K cols 128..255
            short8 Aq, Bk;
            #pragma unroll
            for (int j = 0; j < 8; ++j) {
                Aq[j] = (short)s_qk[abase + j * 48];
                Bk[j] = (short)s_qk[bbase + j * 48];
            }
            f32x4 sc = {0.f, 0.f, 0.f, 0.f};
            __builtin_amdgcn_s_setprio(1);
            scf[i] = __builtin_amdgcn_mfma_f32_16x16x32_bf16(Aq, Bk, sc, 0, 0, 0);
            __builtin_amdgcn_s_setprio(0);
        }
    }
    __syncthreads();   // s_qk now dead -> its space becomes s_ctx + s_pp

    // ---- SCORES phase 2: max-free softmax in C-regs -> s_pp (wave-local) ----
    {
        #pragma unroll
        for (int i = 0; i < 2; ++i) {
            u16* pp = s_pp + (wv * 2 + i) * 256;
            f32x4 pr4;
            #pragma unroll
            for (int r = 0; r < 4; ++r) {
                int mr = lg * 4 + r;
                int prr = (mr >= 6 && mr < 12) ? 1 : 0;
                // softmax is shift-invariant; scores are O(1), clamp@60 guards overflow
                float v = fminf(scf[i][r] * 0.17677669529663687f, 60.f);
                bool inR = (col >= 6 * prr) && (col < 6 * prr + 6);
                float e = inR ? __expf(v) : 0.f;
                float s = e;
                #pragma unroll
                for (int off = 1; off < 16; off <<= 1)
                    s += __shfl_xor(s, off, 16);
                pr4[r] = (mr < 12) ? (e / s) : 0.f;
            }
            uint2 w;
            w.x = cvt_pk_bf16(pr4[0], pr4[1]);
            w.y = cvt_pk_bf16(pr4[2], pr4[3]);
            *(uint2*)&pp[col * 16 + lg * 4] = w;   // Ppad[k=col][m quad]
        }
    }
    // no barrier: s_pp is wave-local (same-wave DS ops are program-ordered;
    // s_vt/s_ctx overlay protected by the scores-P1 barrier)

    // ---- PV: ctx = P @ V via MFMA (A from s_pp block-diag, B 2x b64 from s_vt) ----
    {
        const int rb = wv;
        #pragma unroll
        for (int i = 0; i < 2; ++i) {
            const int hp = i;
            u16* pp = s_pp + (wv * 2 + i) * 256;
            short8 Ap;
            if (lg < 2) {
                #pragma unroll
                for (int j = 0; j < 8; ++j)
                    Ap[j] = (short)pp[(lg * 8 + j) * 16 + col];
            } else {
                #pragma unroll
                for (int j = 0; j < 8; ++j) Ap[j] = 0;
            }
            int g2 = rb * 2 + hp;
            #pragma unroll
            for (int ch = 0; ch < 2; ++ch) {
                // 12-wide rows: two 8B-aligned b64 reads; upper half's last 4 slots
                // (k=12..15) read the next row / region (finite) x pp rows 12..15 == 0.
                int vbase = ((g2 * 2 + ch) * 16 + col) * 12 + ((lg & 1) * 8);
                uint2 vlo = *(const uint2*)&s_vt[vbase];
                uint2 vhi = *(const uint2*)&s_vt[vbase + 4];
                union { uint4 u; short8 s; } cvu;
                cvu.u.x = vlo.x; cvu.u.y = vlo.y; cvu.u.z = vhi.x; cvu.u.w = vhi.y;
                short8 Bv = cvu.s;
                f32x4 c = {0.f, 0.f, 0.f, 0.f};
                __builtin_amdgcn_s_setprio(1);
                c = __builtin_amdgcn_mfma_f32_16x16x32_bf16(Ap, Bv, c, 0, 0, 0);
                __builtin_amdgcn_s_setprio(0);
                #pragma unroll
                for (int r = 0; r < 4; ++r) {
                    int mr = lg * 4 + r;
                    if (mr < 12) {
                        int pq = mr >= 6 ? 1 : 0;
                        int qi = mr - 6 * pq;
                        int token = qi * 8 + rb;
                        int d = (hp * 2 + pq) * 32 + ch * 16 + col;
                        s_ctx[((token * 16 + ((d >> 3) ^ (token & 15))) << 3) + (d & 7)] = f2bf(c[r]);
                    }
                }
            }
        }
    }
    __syncthreads();   // s_pp dead -> region becomes s_part

    // ---- S6 (8-wave): out-proj transposed + residual + LN w/ cross-wave partials ----
    {
        const int mo = wv;                     // this wave's 16 output cols
        short8 Afr[4];
        #pragma unroll
        for (int kk = 0; kk < 4; ++kk)
            Afr[kk] = *(const short8*)&ws[OFF_WO + (((mo * 4 + kk) * 64 + lane) << 3)];
        f32x4 biasv = *(const f32x4*)&bo[mo * 16 + lg * 4];
        f32x4 accs[3];
        #pragma unroll
        for (int tt = 0; tt < 3; ++tt) {
            int tokr = tt * 16 + col;
            f32x4 acc = biasv;
            short8 Bf[4];
            #pragma unroll
            for (int kk = 0; kk < 4; ++kk)
                Bf[kk] = *(const short8*)&s_ctx[(tokr * 16 + ((kk * 4 + lg) ^ (tokr & 15))) << 3];
            __builtin_amdgcn_s_setprio(1);
            #pragma unroll
            for (int kk = 0; kk < 4; ++kk)
                acc = __builtin_amdgcn_mfma_f32_16x16x32_bf16(Afr[kk], Bf[kk], acc, 0, 0, 0);
            __builtin_amdgcn_s_setprio(0);
            const u16* rp = &s_tok[((tokr * 16 + ((mo * 2 + (lg >> 1)) ^ (tokr & 15))) << 3) + (lg & 1) * 4];
            #pragma unroll
            for (int r = 0; r < 4; ++r) acc[r] += bf2f(rp[r]);
            accs[tt] = acc;
            float s1 = acc[0] + acc[1] + acc[2] + acc[3];
            float s2 = acc[0]*acc[0] + acc[1]*acc[1] + acc[2]*acc[2] + acc[3]*acc[3];
            s1 += __shfl_xor(s1, 16, 64); s1 += __shfl_xor(s1, 32, 64);
            s2 += __shfl_xor(s2, 16, 64); s2 += __shfl_xor(s2, 32, 64);
            if (lg == 0) {
                float2 pw; pw.x = s1; pw.y = s2;
                *(float2*)&s_part[(tokr * 8 + wv) * 2] = pw;
            }
        }
        __syncthreads();
        f32x4 gv = *(const f32x4*)&gg[mo * 16 + lg * 4];
        f32x4 bv = *(const f32x4*)&beta[mo * 16 + lg * 4];
        #pragma unroll
        for (int tt = 0; tt < 3; ++tt) {
            int tokr = tt * 16 + col;
            const float* pr = &s_part[tokr * 16];
            f32x4 p0 = *(const f32x4*)pr;
            f32x4 p1 = *(const f32x4*)(pr + 4);
            f32x4 p2 = *(const f32x4*)(pr + 8);
            f32x4 p3 = *(const f32x4*)(pr + 12);
            float S1 = p0[0]+p0[2]+p1[0]+p1[2]+p2[0]+p2[2]+p3[0]+p3[2];
            float S2 = p0[1]+p0[3]+p1[1]+p1[3]+p2[1]+p2[3]+p3[1]+p3[3];
            float mu = S1 * (1.f / 128.f);
            float var = S2 * (1.f / 128.f) - mu * mu;
            float rs = rsqrtf(var + LN_EPS);
            f32x4 a = accs[tt];
            uint2 w;
            w.x = cvt_pk_bf16((a[0]-mu)*rs*gv[0]+bv[0], (a[1]-mu)*rs*gv[1]+bv[1]);
            w.y = cvt_pk_bf16((a[2]-mu)*rs*gv[2]+bv[2], (a[3]-mu)*rs*gv[3]+bv[3]);
            *(uint2*)&s_tok[((tokr * 16 + ((mo * 2 + (lg >> 1)) ^ (tokr & 15))) << 3) + (lg & 1) * 4] = w;
        }
    }
    __syncthreads();

    // ---- S7: mean-pool over 6 tokens ----
    if (t < 128) {
        int row = t >> 4, gch = t & 15;
        float fa[8] = {0, 0, 0, 0, 0, 0, 0, 0};
        #pragma unroll
        for (int c = 0; c < 6; ++c) {
            int tok = c * 8 + row;
            short8 v = *(const short8*)&s_tok[(tok * 16 + (gch ^ (tok & 15))) << 3];
            #pragma unroll
            for (int j = 0; j < 8; ++j) fa[j] += bf2f((u16)v[j]);
        }
        short8 o;
        #pragma unroll
        for (int j = 0; j < 8; ++j) o[j] = (short)f2bf(fa[j] * (1.f / 6.f));
        *(short8*)&s_pool[(row * 16 + (gch ^ row)) << 3] = o;
    }
    __syncthreads();

    // ---- S8: pooled @ Wp + bp, ReLU -> direct coalesced global store ----
    {
        int arow = col & 7;
        short8 A[4];
        #pragma unroll
        for (int kk = 0; kk < 4; ++kk) {
            int g = kk * 4 + lg;
            A[kk] = *(const short8*)&s_pool[(arow * 16 + (g ^ arow)) << 3];
        }
        #pragma unroll
        for (int ni = 0; ni < 2; ++ni) {
            int n = wv * 2 + ni;
            float b = bp[n * 16 + col];
            f32x4 acc = {b, b, b, b};
            __builtin_amdgcn_s_setprio(1);
            #pragma unroll
            for (int kk = 0; kk < 4; ++kk) {
                short8 Bf = *(const short8*)&ws[OFF_WP + (((n * 4 + kk) * 64 + lane) << 3)];
                acc = __builtin_amdgcn_mfma_f32_16x16x32_bf16(A[kk], Bf, acc, 0, 0, 0);
            }
            __builtin_amdgcn_s_setprio(0);
            if (lg < 2) {
                // D[m=lg*4+r][n=col]: per (n,r), lanes 0-15 / 16-31 each cover one
                // contiguous 64B row segment -> coalesced without LDS staging.
                #pragma unroll
                for (int r = 0; r < 4; ++r) {
                    int row = lg * 4 + r;
                    out[((size_t)blk * 8 + row) * 256 + n * 16 + col] = fmaxf(acc[r], 0.f);
                }
            }
        }
    }
}

extern "C" void kernel_launch(void* const* d_in, const int* in_sizes, int n_in,
                              void* d_out, int out_size, void* d_ws, size_t ws_size,
                              hipStream_t stream) {
    const float* x    = (const float*)d_in[0];
    const float* Wv   = (const float*)d_in[1];
    const float* bv   = (const float*)d_in[2];
    const float* Wm   = (const float*)d_in[3];
    const float* bm   = (const float*)d_in[4];
    const float* Wi   = (const float*)d_in[5];
    const float* bi   = (const float*)d_in[6];
    const float* Wb   = (const float*)d_in[7];
    const float* bb   = (const float*)d_in[8];
    const float* Wc   = (const float*)d_in[9];
    const float* bc   = (const float*)d_in[10];
    const float* Wf   = (const float*)d_in[11];
    const float* bf_  = (const float*)d_in[12];
    const float* Pv   = (const float*)d_in[13];
    const float* pv   = (const float*)d_in[14];
    const float* Pm   = (const float*)d_in[15];
    const float* pm   = (const float*)d_in[16];
    const float* Pi   = (const float*)d_in[17];
    const float* pii  = (const float*)d_in[18];
    const float* Pb   = (const float*)d_in[19];
    const float* pb   = (const float*)d_in[20];
    const float* Pc   = (const float*)d_in[21];
    const float* pc   = (const float*)d_in[22];
    const float* Pf   = (const float*)d_in[23];
    const float* pf   = (const float*)d_in[24];
    const float* Wqkv = (const float*)d_in[25];
    const float* bqkv = (const float*)d_in[26];
    const float* Wo   = (const float*)d_in[27];
    const float* bo   = (const float*)d_in[28];
    const float* gg   = (const float*)d_in[29];
    const float* beta = (const float*)d_in[30];
    const float* Wp   = (const float*)d_in[31];
    const float* bp   = (const float*)d_in[32];
    float* out = (float*)d_out;
    u16* ws = (u16*)d_ws;

    convert_weights<<<(CW_TOTAL + 511) / 512, 512, 0, stream>>>(
        Wqkv, Wo, Wp, Pv, Pm, Pi, Pb, Pc, Pf,
        Wv, Wm, Wi, Wb, Wc, Wf, bv, bm, bi, bb, bc, bf_, ws);

    const int Bn = in_sizes[0] / 29;       // 65536
    asmlp_mfma<<<Bn / 8, 512, 0, stream>>>(
        x, pv, pm, pii, pb, pc, pf,
        bqkv, bo, gg, beta, bp, ws, out);
}

// Round 17
// 277.744 us; speedup vs baseline: 1.0209x; 1.0209x over previous
//
#include <hip/hip_runtime.h>
#include <math.h>

typedef float f32x4 __attribute__((ext_vector_type(4)));
typedef short short8 __attribute__((ext_vector_type(8)));
typedef unsigned short u16;

#define LN_EPS 1e-5f

static __device__ __forceinline__ unsigned cvt_pk_bf16(float lo, float hi) {
    unsigned r;
    asm("v_cvt_pk_bf16_f32 %0, %1, %2" : "=v"(r) : "v"(lo), "v"(hi));
    return r;
}
static __device__ __forceinline__ u16 f2bf(float f) { return (u16)cvt_pk_bf16(f, f); }
static __device__ __forceinline__ float bf2f(u16 u) {
    return __uint_as_float(((unsigned)u) << 16);
}

// ws segment offsets (u16 elements). Fragment-linear layout (works as A- or B-operand):
// idx = ((ntile*Ksteps + kk)*64 + lane)*8 + j -> W[kk*32+(lane>>4)*8+j][ntile*16+(lane&15)]
#define OFF_QKV 0
#define OFF_WO  49152
#define OFF_WP  65536
#define OFF_PV  98304
#define OFF_PM  106496
#define OFF_PI  114688
#define OFF_PB  118784
#define OFF_PC  122880
#define OFF_PF  131072
#define OFF_WENC 147456     // block-diag encoder weight, hi/lo stacked: 24 ntiles x 2 ksteps
#define OFF_BENC 172032     // f32 region (384 floats) starts at this u16 index
#define CW_TOTAL 172416

__global__ __launch_bounds__(512) void convert_weights(
    const float* __restrict__ Wqkv, const float* __restrict__ Wo, const float* __restrict__ Wp,
    const float* __restrict__ Pv, const float* __restrict__ Pm, const float* __restrict__ Pi,
    const float* __restrict__ Pb, const float* __restrict__ Pc, const float* __restrict__ Pf,
    const float* __restrict__ Wv, const float* __restrict__ Wm, const float* __restrict__ Wi,
    const float* __restrict__ Wb, const float* __restrict__ Wc, const float* __restrict__ Wf,
    const float* __restrict__ bv, const float* __restrict__ bm, const float* __restrict__ bi,
    const float* __restrict__ bb, const float* __restrict__ bc, const float* __restrict__ bf_,
    u16* __restrict__ ws)
{
    int gid = blockIdx.x * 512 + threadIdx.x;
    if (gid < OFF_WENC) {
        const float* src; int N, Ksteps, local;
        if (gid < OFF_WO)      { src = Wqkv; N = 384; Ksteps = 4; local = gid; }
        else if (gid < OFF_WP) { src = Wo;   N = 128; Ksteps = 4; local = gid - OFF_WO; }
        else if (gid < OFF_PV) { src = Wp;   N = 256; Ksteps = 4; local = gid - OFF_WP; }
        else if (gid < OFF_PM) { src = Pv;   N = 128; Ksteps = 2; local = gid - OFF_PV; }
        else if (gid < OFF_PI) { src = Pm;   N = 128; Ksteps = 2; local = gid - OFF_PM; }
        else if (gid < OFF_PB) { src = Pi;   N = 128; Ksteps = 1; local = gid - OFF_PI; }
        else if (gid < OFF_PC) { src = Pb;   N = 128; Ksteps = 1; local = gid - OFF_PB; }
        else if (gid < OFF_PF) { src = Pc;   N = 128; Ksteps = 2; local = gid - OFF_PC; }
        else                   { src = Pf;   N = 128; Ksteps = 4; local = gid - OFF_PF; }
        int j  = local & 7;
        int l  = (local >> 3) & 63;
        int r2 = local >> 9;
        int kk = r2 % Ksteps;
        int nt = r2 / Ksteps;
        int srow = kk * 32 + (l >> 4) * 8 + j;
        int scol = nt * 16 + (l & 15);
        ws[gid] = f2bf(src[srow * N + scol]);
    } else if (gid < OFF_BENC) {
        int local = gid - OFF_WENC;
        int j = local & 7, l = (local >> 3) & 63, r2 = local >> 9;
        int kk = r2 & 1, nt = r2 >> 1;
        int k = kk * 32 + (l >> 4) * 8 + j;
        int r = k & 31;                    // x input dim (0..31, valid <29)
        int scol = nt * 16 + (l & 15);     // 0..383
        const float* W; int cb, xo, din, dout;
        if (scol < 64)       { W = Wv; cb = 0;   xo = 0;  din = 3;  dout = 64; }
        else if (scol < 128) { W = Wm; cb = 64;  xo = 3;  din = 5;  dout = 64; }
        else if (scol < 160) { W = Wi; cb = 128; xo = 8;  din = 2;  dout = 32; }
        else if (scol < 192) { W = Wb; cb = 160; xo = 10; din = 3;  dout = 32; }
        else if (scol < 256) { W = Wc; cb = 192; xo = 13; din = 6;  dout = 64; }
        else                 { W = Wf; cb = 256; xo = 19; din = 10; dout = 128; }
        int rr = r - xo;
        float val = (r < 29 && rr >= 0 && rr < din) ? W[rr * dout + (scol - cb)] : 0.f;
        ws[gid] = f2bf(val);
    } else if (gid < CW_TOTAL) {
        int j = gid - OFF_BENC;
        const float* b; int off;
        if (j < 64)       { b = bv;  off = 0; }
        else if (j < 128) { b = bm;  off = 64; }
        else if (j < 160) { b = bi;  off = 128; }
        else if (j < 192) { b = bb;  off = 160; }
        else if (j < 256) { b = bc;  off = 192; }
        else              { b = bf_; off = 256; }
        ((float*)(ws + OFF_BENC))[j] = b[j - off];
    }
}

// 8 rows/block, 48 tokens (token = comp*8 + row), 512 threads = 8 waves (wave = row).
// r15 verbatim (validated best, 277.7 us): r13 + S8 direct global store.
__global__ __launch_bounds__(512, 4) void asmlp_mfma(
    const float* __restrict__ x,
    const float* __restrict__ pv, const float* __restrict__ pm,
    const float* __restrict__ pi_, const float* __restrict__ pb_,
    const float* __restrict__ pc_, const float* __restrict__ pf_,
    const float* __restrict__ bqkv, const float* __restrict__ bo,
    const float* __restrict__ gg, const float* __restrict__ beta,
    const float* __restrict__ bp,
    const u16* __restrict__ ws,
    float* __restrict__ out)
{
    const int blk  = blockIdx.x;
    const int t    = threadIdx.x;
    const int lane = t & 63;
    const int wv   = t >> 6;
    const int col  = lane & 15;
    const int lg   = lane >> 4;

    __shared__ __attribute__((aligned(16))) u16 sm[24576];   // 49152 B
    u16*   s_tok  = sm;                      // [48 tok][16 g][8] swz g^(tok&15)      12288 B
    u16*   s_vt   = sm + 6144;               // [16 g2][2 ch][16 nn][12 k=p*6+c2]     12288 B
    u16*   s_qk   = sm + 12288;              // col-major [256 col][48 tok]           24576 B
    u16*   s_xa   = sm + 12288;              // [8 row][64 k] hi/lo (overlay qk, S0-S2)
    u16*   s_h    = sm + 12800;              // [8 row][48 g][8] (overlay qk, S1-S2)
    u16*   s_ctx  = sm + 12288;              // [48 tok][16 g][8] (overlay qk, after scores)
    u16*   s_pp   = sm + 18432;              // [8 wv][2 slot][16 k][16 m] (overlay qk upper)
    float* s_part = (float*)(sm + 18432);    // [48 tok][8 wv][2] f32 (overlay pp; S6)
    u16*   s_pool = sm + 6144;               // [8 row][16 g][8] (overlay vt; S7+)

    // ---- S0: stage x as hi/lo bf16 (exact fp32 split), granule-swizzled ----
    if (t < 232) {
        int row = t / 29, cc = t - row * 29;
        float f = x[(size_t)blk * 232 + t];
        u16 hi = f2bf(f);
        float lo = f - bf2f(hi);
        s_xa[row * 64 + (((cc >> 3) ^ (row & 3)) << 3) + (cc & 7)] = hi;
        int c2 = cc + 32;
        s_xa[row * 64 + (((c2 >> 3) ^ (row & 3)) << 3) + (c2 & 7)] = f2bf(lo);
    }
    if (t < 48) {
        int row = t / 6, sl = t - (t / 6) * 6;
        int k = (sl < 3) ? (29 + sl) : (58 + sl);   // 29..31, 61..63
        s_xa[row * 64 + (((k >> 3) ^ (row & 3)) << 3) + (k & 7)] = 0;
    }
    __syncthreads();

    // ---- S1: encoders, transposed MFMA: C[enc_col][row] ----
    {
        int row8 = col & 7;
        short8 B0 = *(const short8*)&s_xa[row8 * 64 + ((lg ^ (row8 & 3)) << 3)];
        short8 B1 = *(const short8*)&s_xa[row8 * 64 + (((4 + lg) ^ (row8 & 3)) << 3)];
        const float* benc = (const float*)(ws + OFF_BENC);
        #pragma unroll
        for (int q = 0; q < 3; ++q) {
            int nt = wv * 3 + q;
            f32x4 acc = *(const f32x4*)&benc[nt * 16 + lg * 4];
            short8 A0 = *(const short8*)&ws[OFF_WENC + (((nt * 2 + 0) * 64 + lane) << 3)];
            short8 A1 = *(const short8*)&ws[OFF_WENC + (((nt * 2 + 1) * 64 + lane) << 3)];
            acc = __builtin_amdgcn_mfma_f32_16x16x32_bf16(A0, B0, acc, 0, 0, 0);
            acc = __builtin_amdgcn_mfma_f32_16x16x32_bf16(A1, B1, acc, 0, 0, 0);
            if (col < 8) {
                int ge = nt * 2 + (lg >> 1);
                uint2 w;
                w.x = cvt_pk_bf16(fmaxf(acc[0], 0.f), fmaxf(acc[1], 0.f));
                w.y = cvt_pk_bf16(fmaxf(acc[2], 0.f), fmaxf(acc[3], 0.f));
                *(uint2*)&s_h[((col * 48 + (ge ^ col)) << 3) + (lg & 1) * 4] = w;
            }
        }
    }
    __syncthreads();

    // ---- S2: projections, transposed: C[proj_col][row] ----
    #pragma unroll
    for (int q = 0; q < 6; ++q) {
        int unit = wv * 6 + q;
        int c = unit >> 3, n = unit & 7;
        const float* bias; int ks, hg, wso;
        switch (c) {
            case 0:  bias = pv;  ks = 2; hg = 0;  wso = OFF_PV; break;
            case 1:  bias = pm;  ks = 2; hg = 8;  wso = OFF_PM; break;
            case 2:  bias = pi_; ks = 1; hg = 16; wso = OFF_PI; break;
            case 3:  bias = pb_; ks = 1; hg = 20; wso = OFF_PB; break;
            case 4:  bias = pc_; ks = 2; hg = 24; wso = OFF_PC; break;
            default: bias = pf_; ks = 4; hg = 32; wso = OFF_PF; break;
        }
        f32x4 acc = *(const f32x4*)&bias[n * 16 + lg * 4];
        int hrow = col & 7;
        for (int kk = 0; kk < ks; ++kk) {
            short8 A = *(const short8*)&ws[wso + (((n * ks + kk) * 64 + lane) << 3)];
            short8 B = *(const short8*)&s_h[(hrow * 48 + ((hg + kk * 4 + lg) ^ hrow)) << 3];
            acc = __builtin_amdgcn_mfma_f32_16x16x32_bf16(A, B, acc, 0, 0, 0);
        }
        if (col < 8) {
            int tok = c * 8 + col;
            int gt = n * 2 + (lg >> 1);
            uint2 w;
            w.x = cvt_pk_bf16(acc[0], acc[1]);
            w.y = cvt_pk_bf16(acc[2], acc[3]);
            *(uint2*)&s_tok[((tok * 16 + (gt ^ (tok & 15))) << 3) + (lg & 1) * 4] = w;
        }
    }
    __syncthreads();

    // ---- S3: QKV (MFMA). Q/K -> col-major s_qk (cvt_pk + b64); V -> s_vt [*12] ----
    {
        short8 Bf[3][4];
        float  bb_[3];
        #pragma unroll
        for (int ni = 0; ni < 3; ++ni) {
            int n = wv * 3 + ni;
            bb_[ni] = bqkv[n * 16 + col];
            #pragma unroll
            for (int kk = 0; kk < 4; ++kk)
                Bf[ni][kk] = *(const short8*)&ws[OFF_QKV + (((n * 4 + kk) * 64 + lane) << 3)];
        }
        for (int mt = 0; mt < 3; ++mt) {
            short8 A[4];
            int arow = mt * 16 + col;
            #pragma unroll
            for (int kk = 0; kk < 4; ++kk) {
                int g = kk * 4 + lg;
                A[kk] = *(const short8*)&s_tok[(arow * 16 + (g ^ (arow & 15))) << 3];
            }
            #pragma unroll
            for (int ni = 0; ni < 3; ++ni) {
                f32x4 acc = {bb_[ni], bb_[ni], bb_[ni], bb_[ni]};
                #pragma unroll
                for (int kk = 0; kk < 4; ++kk)
                    acc = __builtin_amdgcn_mfma_f32_16x16x32_bf16(A[kk], Bf[ni][kk], acc, 0, 0, 0);
                int cn = wv * 3 + ni;
                int cg = cn * 16 + col;                 // global qkv column
                if (cn < 16) {
                    // Q/K: col-major, token index XOR-swizzled by ((cg>>3)&3)<<2
                    int q4 = ((cg >> 3) & 3) << 2;
                    int tb = (mt * 16 + lg * 4) ^ q4;
                    uint2 w;
                    w.x = cvt_pk_bf16(acc[0], acc[1]);
                    w.y = cvt_pk_bf16(acc[2], acc[3]);
                    *(uint2*)&s_qk[cg * 48 + tb] = w;
                } else {
                    int d = cg - 256;
                    int h = d >> 5, ch = (d >> 4) & 1, nn = d & 15;
                    #pragma unroll
                    for (int r = 0; r < 4; ++r) {
                        int token = mt * 16 + lg * 4 + r;
                        int c2 = token >> 3, rb = token & 7;
                        int g2 = rb * 2 + (h >> 1);
                        int kidx = (h & 1) * 6 + c2;
                        s_vt[((g2 * 2 + ch) * 16 + nn) * 12 + kidx] = f2bf(acc[r]);
                    }
                }
            }
        }
    }
    __syncthreads();

    // ---- SCORES phase 1: MFMAs only (last readers of s_qk) ----
    f32x4 scf[2];
    {
        const int rb = wv;
        #pragma unroll
        for (int i = 0; i < 2; ++i) {
            const int hp = i;
            int p  = (col >= 6 && col < 12) ? 1 : 0;
            int qi = (col < 6) ? col : ((col < 12) ? col - 6 : 0);
            int tt = qi * 8 + rb;
            int h  = hp * 2 + p;
            int tsw = tt ^ (lg << 2);
            int abase = (h * 32 + lg * 8) * 48 + tsw;          // Q cols 0..127
            int bbase = (128 + h * 32 + lg * 8) * 48 + tsw;    // K cols 128..255
            short8 Aq, Bk;
            #pragma unroll
            for (int j = 0; j < 8; ++j) {
                Aq[j] = (short)s_qk[abase + j * 48];
                Bk[j] = (short)s_qk[bbase + j * 48];
            }
            f32x4 sc = {0.f, 0.f, 0.f, 0.f};
            scf[i] = __builtin_amdgcn_mfma_f32_16x16x32_bf16(Aq, Bk, sc, 0, 0, 0);
        }
    }
    __syncthreads();   // s_qk now dead -> its space becomes s_ctx + s_pp

    // ---- SCORES phase 2: max-free softmax in C-regs -> s_pp (wave-local) ----
    {
        #pragma unroll
        for (int i = 0; i < 2; ++i) {
            u16* pp = s_pp + (wv * 2 + i) * 256;
            f32x4 pr4;
            #pragma unroll
            for (int r = 0; r < 4; ++r) {
                int mr = lg * 4 + r;
                int prr = (mr >= 6 && mr < 12) ? 1 : 0;
                // softmax is shift-invariant; scores are O(1), clamp@60 guards overflow
                float v = fminf(scf[i][r] * 0.17677669529663687f, 60.f);
                bool inR = (col >= 6 * prr) && (col < 6 * prr + 6);
                float e = inR ? __expf(v) : 0.f;
                float s = e;
                #pragma unroll
                for (int off = 1; off < 16; off <<= 1)
                    s += __shfl_xor(s, off, 16);
                pr4[r] = (mr < 12) ? (e / s) : 0.f;
            }
            uint2 w;
            w.x = cvt_pk_bf16(pr4[0], pr4[1]);
            w.y = cvt_pk_bf16(pr4[2], pr4[3]);
            *(uint2*)&pp[col * 16 + lg * 4] = w;   // Ppad[k=col][m quad]
        }
    }
    // no barrier: s_pp is wave-local (same-wave DS ops are program-ordered;
    // s_vt/s_ctx overlay protected by the scores-P1 barrier)

    // ---- PV: ctx = P @ V via MFMA (A from s_pp block-diag, B 2x b64 from s_vt) ----
    {
        const int rb = wv;
        #pragma unroll
        for (int i = 0; i < 2; ++i) {
            const int hp = i;
            u16* pp = s_pp + (wv * 2 + i) * 256;
            short8 Ap;
            if (lg < 2) {
                #pragma unroll
                for (int j = 0; j < 8; ++j)
                    Ap[j] = (short)pp[(lg * 8 + j) * 16 + col];
            } else {
                #pragma unroll
                for (int j = 0; j < 8; ++j) Ap[j] = 0;
            }
            int g2 = rb * 2 + hp;
            #pragma unroll
            for (int ch = 0; ch < 2; ++ch) {
                // 12-wide rows: two 8B-aligned b64 reads; upper half's last 4 slots
                // (k=12..15) read the next row / region (finite) x pp rows 12..15 == 0.
                int vbase = ((g2 * 2 + ch) * 16 + col) * 12 + ((lg & 1) * 8);
                uint2 vlo = *(const uint2*)&s_vt[vbase];
                uint2 vhi = *(const uint2*)&s_vt[vbase + 4];
                union { uint4 u; short8 s; } cvu;
                cvu.u.x = vlo.x; cvu.u.y = vlo.y; cvu.u.z = vhi.x; cvu.u.w = vhi.y;
                short8 Bv = cvu.s;
                f32x4 c = {0.f, 0.f, 0.f, 0.f};
                c = __builtin_amdgcn_mfma_f32_16x16x32_bf16(Ap, Bv, c, 0, 0, 0);
                #pragma unroll
                for (int r = 0; r < 4; ++r) {
                    int mr = lg * 4 + r;
                    if (mr < 12) {
                        int pq = mr >= 6 ? 1 : 0;
                        int qi = mr - 6 * pq;
                        int token = qi * 8 + rb;
                        int d = (hp * 2 + pq) * 32 + ch * 16 + col;
                        s_ctx[((token * 16 + ((d >> 3) ^ (token & 15))) << 3) + (d & 7)] = f2bf(c[r]);
                    }
                }
            }
        }
    }
    __syncthreads();   // s_pp dead -> region becomes s_part

    // ---- S6 (8-wave): out-proj transposed + residual + LN w/ cross-wave partials ----
    {
        const int mo = wv;                     // this wave's 16 output cols
        short8 Afr[4];
        #pragma unroll
        for (int kk = 0; kk < 4; ++kk)
            Afr[kk] = *(const short8*)&ws[OFF_WO + (((mo * 4 + kk) * 64 + lane) << 3)];
        f32x4 biasv = *(const f32x4*)&bo[mo * 16 + lg * 4];
        f32x4 accs[3];
        #pragma unroll
        for (int tt = 0; tt < 3; ++tt) {
            int tokr = tt * 16 + col;
            f32x4 acc = biasv;
            #pragma unroll
            for (int kk = 0; kk < 4; ++kk) {
                short8 Bf = *(const short8*)&s_ctx[(tokr * 16 + ((kk * 4 + lg) ^ (tokr & 15))) << 3];
                acc = __builtin_amdgcn_mfma_f32_16x16x32_bf16(Afr[kk], Bf, acc, 0, 0, 0);
            }
            const u16* rp = &s_tok[((tokr * 16 + ((mo * 2 + (lg >> 1)) ^ (tokr & 15))) << 3) + (lg & 1) * 4];
            #pragma unroll
            for (int r = 0; r < 4; ++r) acc[r] += bf2f(rp[r]);
            accs[tt] = acc;
            float s1 = acc[0] + acc[1] + acc[2] + acc[3];
            float s2 = acc[0]*acc[0] + acc[1]*acc[1] + acc[2]*acc[2] + acc[3]*acc[3];
            s1 += __shfl_xor(s1, 16, 64); s1 += __shfl_xor(s1, 32, 64);
            s2 += __shfl_xor(s2, 16, 64); s2 += __shfl_xor(s2, 32, 64);
            if (lg == 0) {
                float2 pw; pw.x = s1; pw.y = s2;
                *(float2*)&s_part[(tokr * 8 + wv) * 2] = pw;
            }
        }
        __syncthreads();
        f32x4 gv = *(const f32x4*)&gg[mo * 16 + lg * 4];
        f32x4 bv = *(const f32x4*)&beta[mo * 16 + lg * 4];
        #pragma unroll
        for (int tt = 0; tt < 3; ++tt) {
            int tokr = tt * 16 + col;
            const float* pr = &s_part[tokr * 16];
            f32x4 p0 = *(const f32x4*)pr;
            f32x4 p1 = *(const f32x4*)(pr + 4);
            f32x4 p2 = *(const f32x4*)(pr + 8);
            f32x4 p3 = *(const f32x4*)(pr + 12);
            float S1 = p0[0]+p0[2]+p1[0]+p1[2]+p2[0]+p2[2]+p3[0]+p3[2];
            float S2 = p0[1]+p0[3]+p1[1]+p1[3]+p2[1]+p2[3]+p3[1]+p3[3];
            float mu = S1 * (1.f / 128.f);
            float var = S2 * (1.f / 128.f) - mu * mu;
            float rs = rsqrtf(var + LN_EPS);
            f32x4 a = accs[tt];
            uint2 w;
            w.x = cvt_pk_bf16((a[0]-mu)*rs*gv[0]+bv[0], (a[1]-mu)*rs*gv[1]+bv[1]);
            w.y = cvt_pk_bf16((a[2]-mu)*rs*gv[2]+bv[2], (a[3]-mu)*rs*gv[3]+bv[3]);
            *(uint2*)&s_tok[((tokr * 16 + ((mo * 2 + (lg >> 1)) ^ (tokr & 15))) << 3) + (lg & 1) * 4] = w;
        }
    }
    __syncthreads();

    // ---- S7: mean-pool over 6 tokens ----
    if (t < 128) {
        int row = t >> 4, gch = t & 15;
        float fa[8] = {0, 0, 0, 0, 0, 0, 0, 0};
        #pragma unroll
        for (int c = 0; c < 6; ++c) {
            int tok = c * 8 + row;
            short8 v = *(const short8*)&s_tok[(tok * 16 + (gch ^ (tok & 15))) << 3];
            #pragma unroll
            for (int j = 0; j < 8; ++j) fa[j] += bf2f((u16)v[j]);
        }
        short8 o;
        #pragma unroll
        for (int j = 0; j < 8; ++j) o[j] = (short)f2bf(fa[j] * (1.f / 6.f));
        *(short8*)&s_pool[(row * 16 + (gch ^ row)) << 3] = o;
    }
    __syncthreads();

    // ---- S8: pooled @ Wp + bp, ReLU -> direct coalesced global store ----
    {
        int arow = col & 7;
        short8 A[4];
        #pragma unroll
        for (int kk = 0; kk < 4; ++kk) {
            int g = kk * 4 + lg;
            A[kk] = *(const short8*)&s_pool[(arow * 16 + (g ^ arow)) << 3];
        }
        #pragma unroll
        for (int ni = 0; ni < 2; ++ni) {
            int n = wv * 2 + ni;
            float b = bp[n * 16 + col];
            f32x4 acc = {b, b, b, b};
            #pragma unroll
            for (int kk = 0; kk < 4; ++kk) {
                short8 Bf = *(const short8*)&ws[OFF_WP + (((n * 4 + kk) * 64 + lane) << 3)];
                acc = __builtin_amdgcn_mfma_f32_16x16x32_bf16(A[kk], Bf, acc, 0, 0, 0);
            }
            if (lg < 2) {
                // D[m=lg*4+r][n=col]: per (n,r), lanes 0-15 / 16-31 each cover one
                // contiguous 64B row segment -> coalesced without LDS staging.
                #pragma unroll
                for (int r = 0; r < 4; ++r) {
                    int row = lg * 4 + r;
                    out[((size_t)blk * 8 + row) * 256 + n * 16 + col] = fmaxf(acc[r], 0.f);
                }
            }
        }
    }
}

extern "C" void kernel_launch(void* const* d_in, const int* in_sizes, int n_in,
                              void* d_out, int out_size, void* d_ws, size_t ws_size,
                              hipStream_t stream) {
    const float* x    = (const float*)d_in[0];
    const float* Wv   = (const float*)d_in[1];
    const float* bv   = (const float*)d_in[2];
    const float* Wm   = (const float*)d_in[3];
    const float* bm   = (const float*)d_in[4];
    const float* Wi   = (const float*)d_in[5];
    const float* bi   = (const float*)d_in[6];
    const float* Wb   = (const float*)d_in[7];
    const float* bb   = (const float*)d_in[8];
    const float* Wc   = (const float*)d_in[9];
    const float* bc   = (const float*)d_in[10];
    const float* Wf   = (const float*)d_in[11];
    const float* bf_  = (const float*)d_in[12];
    const float* Pv   = (const float*)d_in[13];
    const float* pv   = (const float*)d_in[14];
    const float* Pm   = (const float*)d_in[15];
    const float* pm   = (const float*)d_in[16];
    const float* Pi   = (const float*)d_in[17];
    const float* pii  = (const float*)d_in[18];
    const float* Pb   = (const float*)d_in[19];
    const float* pb   = (const float*)d_in[20];
    const float* Pc   = (const float*)d_in[21];
    const float* pc   = (const float*)d_in[22];
    const float* Pf   = (const float*)d_in[23];
    const float* pf   = (const float*)d_in[24];
    const float* Wqkv = (const float*)d_in[25];
    const float* bqkv = (const float*)d_in[26];
    const float* Wo   = (const float*)d_in[27];
    const float* bo   = (const float*)d_in[28];
    const float* gg   = (const float*)d_in[29];
    const float* beta = (const float*)d_in[30];
    const float* Wp   = (const float*)d_in[31];
    const float* bp   = (const float*)d_in[32];
    float* out = (float*)d_out;
    u16* ws = (u16*)d_ws;

    convert_weights<<<(CW_TOTAL + 511) / 512, 512, 0, stream>>>(
        Wqkv, Wo, Wp, Pv, Pm, Pi, Pb, Pc, Pf,
        Wv, Wm, Wi, Wb, Wc, Wf, bv, bm, bi, bb, bc, bf_, ws);

    const int Bn = in_sizes[0] / 29;       // 65536
    asmlp_mfma<<<Bn / 8, 512, 0, stream>>>(
        x, pv, pm, pii, pb, pc, pf,
        bqkv, bo, gg, beta, bp, ws, out);
}

// Round 18
// 271.677 us; speedup vs baseline: 1.0437x; 1.0223x over previous
//
#include <hip/hip_runtime.h>
#include <math.h>

typedef float f32x4 __attribute__((ext_vector_type(4)));
typedef short short8 __attribute__((ext_vector_type(8)));
typedef unsigned short u16;

#define LN_EPS 1e-5f

static __device__ __forceinline__ unsigned cvt_pk_bf16(float lo, float hi) {
    unsigned r;
    asm("v_cvt_pk_bf16_f32 %0, %1, %2" : "=v"(r) : "v"(lo), "v"(hi));
    return r;
}
static __device__ __forceinline__ u16 f2bf(float f) { return (u16)cvt_pk_bf16(f, f); }
static __device__ __forceinline__ float bf2f(u16 u) {
    return __uint_as_float(((unsigned)u) << 16);
}

// ws segment offsets (u16 elements). Fragment-linear layout (works as A- or B-operand):
// idx = ((ntile*Ksteps + kk)*64 + lane)*8 + j -> W[kk*32+(lane>>4)*8+j][ntile*16+(lane&15)]
#define OFF_QKV 0
#define OFF_WO  49152
#define OFF_WP  65536
#define OFF_PV  98304
#define OFF_PM  106496
#define OFF_PI  114688
#define OFF_PB  118784
#define OFF_PC  122880
#define OFF_PF  131072
#define OFF_WENC 147456     // block-diag encoder weight, hi/lo stacked: 24 ntiles x 2 ksteps
#define OFF_BENC 172032     // f32 region (384 floats) starts at this u16 index
#define CW_TOTAL 172416

__global__ __launch_bounds__(512) void convert_weights(
    const float* __restrict__ Wqkv, const float* __restrict__ Wo, const float* __restrict__ Wp,
    const float* __restrict__ Pv, const float* __restrict__ Pm, const float* __restrict__ Pi,
    const float* __restrict__ Pb, const float* __restrict__ Pc, const float* __restrict__ Pf,
    const float* __restrict__ Wv, const float* __restrict__ Wm, const float* __restrict__ Wi,
    const float* __restrict__ Wb, const float* __restrict__ Wc, const float* __restrict__ Wf,
    const float* __restrict__ bv, const float* __restrict__ bm, const float* __restrict__ bi,
    const float* __restrict__ bb, const float* __restrict__ bc, const float* __restrict__ bf_,
    u16* __restrict__ ws)
{
    int gid = blockIdx.x * 512 + threadIdx.x;
    if (gid < OFF_WENC) {
        const float* src; int N, Ksteps, local;
        if (gid < OFF_WO)      { src = Wqkv; N = 384; Ksteps = 4; local = gid; }
        else if (gid < OFF_WP) { src = Wo;   N = 128; Ksteps = 4; local = gid - OFF_WO; }
        else if (gid < OFF_PV) { src = Wp;   N = 256; Ksteps = 4; local = gid - OFF_WP; }
        else if (gid < OFF_PM) { src = Pv;   N = 128; Ksteps = 2; local = gid - OFF_PV; }
        else if (gid < OFF_PI) { src = Pm;   N = 128; Ksteps = 2; local = gid - OFF_PM; }
        else if (gid < OFF_PB) { src = Pi;   N = 128; Ksteps = 1; local = gid - OFF_PI; }
        else if (gid < OFF_PC) { src = Pb;   N = 128; Ksteps = 1; local = gid - OFF_PB; }
        else if (gid < OFF_PF) { src = Pc;   N = 128; Ksteps = 2; local = gid - OFF_PC; }
        else                   { src = Pf;   N = 128; Ksteps = 4; local = gid - OFF_PF; }
        int j  = local & 7;
        int l  = (local >> 3) & 63;
        int r2 = local >> 9;
        int kk = r2 % Ksteps;
        int nt = r2 / Ksteps;
        int srow = kk * 32 + (l >> 4) * 8 + j;
        int scol = nt * 16 + (l & 15);
        ws[gid] = f2bf(src[srow * N + scol]);
    } else if (gid < OFF_BENC) {
        int local = gid - OFF_WENC;
        int j = local & 7, l = (local >> 3) & 63, r2 = local >> 9;
        int kk = r2 & 1, nt = r2 >> 1;
        int k = kk * 32 + (l >> 4) * 8 + j;
        int r = k & 31;                    // x input dim (0..31, valid <29)
        int scol = nt * 16 + (l & 15);     // 0..383
        const float* W; int cb, xo, din, dout;
        if (scol < 64)       { W = Wv; cb = 0;   xo = 0;  din = 3;  dout = 64; }
        else if (scol < 128) { W = Wm; cb = 64;  xo = 3;  din = 5;  dout = 64; }
        else if (scol < 160) { W = Wi; cb = 128; xo = 8;  din = 2;  dout = 32; }
        else if (scol < 192) { W = Wb; cb = 160; xo = 10; din = 3;  dout = 32; }
        else if (scol < 256) { W = Wc; cb = 192; xo = 13; din = 6;  dout = 64; }
        else                 { W = Wf; cb = 256; xo = 19; din = 10; dout = 128; }
        int rr = r - xo;
        float val = (r < 29 && rr >= 0 && rr < din) ? W[rr * dout + (scol - cb)] : 0.f;
        ws[gid] = f2bf(val);
    } else if (gid < CW_TOTAL) {
        int j = gid - OFF_BENC;
        const float* b; int off;
        if (j < 64)       { b = bv;  off = 0; }
        else if (j < 128) { b = bm;  off = 64; }
        else if (j < 160) { b = bi;  off = 128; }
        else if (j < 192) { b = bb;  off = 160; }
        else if (j < 256) { b = bc;  off = 192; }
        else              { b = bf_; off = 256; }
        ((float*)(ws + OFF_BENC))[j] = b[j - off];
    }
}

// 8 rows/block, 48 tokens (token = comp*8 + row), 512 threads = 8 waves (wave = row).
// r15 (validated best) + S3 Wqkv-fragment loads hoisted to kernel entry so their
// L2 latency hides under S0-S2 (value-preserving reorder of pure loads).
__global__ __launch_bounds__(512, 4) void asmlp_mfma(
    const float* __restrict__ x,
    const float* __restrict__ pv, const float* __restrict__ pm,
    const float* __restrict__ pi_, const float* __restrict__ pb_,
    const float* __restrict__ pc_, const float* __restrict__ pf_,
    const float* __restrict__ bqkv, const float* __restrict__ bo,
    const float* __restrict__ gg, const float* __restrict__ beta,
    const float* __restrict__ bp,
    const u16* __restrict__ ws,
    float* __restrict__ out)
{
    const int blk  = blockIdx.x;
    const int t    = threadIdx.x;
    const int lane = t & 63;
    const int wv   = t >> 6;
    const int col  = lane & 15;
    const int lg   = lane >> 4;

    __shared__ __attribute__((aligned(16))) u16 sm[24576];   // 49152 B
    u16*   s_tok  = sm;                      // [48 tok][16 g][8] swz g^(tok&15)      12288 B
    u16*   s_vt   = sm + 6144;               // [16 g2][2 ch][16 nn][12 k=p*6+c2]     12288 B
    u16*   s_qk   = sm + 12288;              // col-major [256 col][48 tok]           24576 B
    u16*   s_xa   = sm + 12288;              // [8 row][64 k] hi/lo (overlay qk, S0-S2)
    u16*   s_h    = sm + 12800;              // [8 row][48 g][8] (overlay qk, S1-S2)
    u16*   s_ctx  = sm + 12288;              // [48 tok][16 g][8] (overlay qk, after scores)
    u16*   s_pp   = sm + 18432;              // [8 wv][2 slot][16 k][16 m] (overlay qk upper)
    float* s_part = (float*)(sm + 18432);    // [48 tok][8 wv][2] f32 (overlay pp; S6)
    u16*   s_pool = sm + 6144;               // [8 row][16 g][8] (overlay vt; S7+)

    // ---- hoisted S3 weight fragments: issue at t=0, consumed after 3 barriers ----
    short8 qkvBf[3][4];
    float  qkvB_[3];
    #pragma unroll
    for (int ni = 0; ni < 3; ++ni) {
        int n = wv * 3 + ni;
        qkvB_[ni] = bqkv[n * 16 + col];
        #pragma unroll
        for (int kk = 0; kk < 4; ++kk)
            qkvBf[ni][kk] = *(const short8*)&ws[OFF_QKV + (((n * 4 + kk) * 64 + lane) << 3)];
    }

    // ---- S0: stage x as hi/lo bf16 (exact fp32 split), granule-swizzled ----
    if (t < 232) {
        int row = t / 29, cc = t - row * 29;
        float f = x[(size_t)blk * 232 + t];
        u16 hi = f2bf(f);
        float lo = f - bf2f(hi);
        s_xa[row * 64 + (((cc >> 3) ^ (row & 3)) << 3) + (cc & 7)] = hi;
        int c2 = cc + 32;
        s_xa[row * 64 + (((c2 >> 3) ^ (row & 3)) << 3) + (c2 & 7)] = f2bf(lo);
    }
    if (t < 48) {
        int row = t / 6, sl = t - (t / 6) * 6;
        int k = (sl < 3) ? (29 + sl) : (58 + sl);   // 29..31, 61..63
        s_xa[row * 64 + (((k >> 3) ^ (row & 3)) << 3) + (k & 7)] = 0;
    }
    __syncthreads();

    // ---- S1: encoders, transposed MFMA: C[enc_col][row] ----
    {
        int row8 = col & 7;
        short8 B0 = *(const short8*)&s_xa[row8 * 64 + ((lg ^ (row8 & 3)) << 3)];
        short8 B1 = *(const short8*)&s_xa[row8 * 64 + (((4 + lg) ^ (row8 & 3)) << 3)];
        const float* benc = (const float*)(ws + OFF_BENC);
        #pragma unroll
        for (int q = 0; q < 3; ++q) {
            int nt = wv * 3 + q;
            f32x4 acc = *(const f32x4*)&benc[nt * 16 + lg * 4];
            short8 A0 = *(const short8*)&ws[OFF_WENC + (((nt * 2 + 0) * 64 + lane) << 3)];
            short8 A1 = *(const short8*)&ws[OFF_WENC + (((nt * 2 + 1) * 64 + lane) << 3)];
            acc = __builtin_amdgcn_mfma_f32_16x16x32_bf16(A0, B0, acc, 0, 0, 0);
            acc = __builtin_amdgcn_mfma_f32_16x16x32_bf16(A1, B1, acc, 0, 0, 0);
            if (col < 8) {
                int ge = nt * 2 + (lg >> 1);
                uint2 w;
                w.x = cvt_pk_bf16(fmaxf(acc[0], 0.f), fmaxf(acc[1], 0.f));
                w.y = cvt_pk_bf16(fmaxf(acc[2], 0.f), fmaxf(acc[3], 0.f));
                *(uint2*)&s_h[((col * 48 + (ge ^ col)) << 3) + (lg & 1) * 4] = w;
            }
        }
    }
    __syncthreads();

    // ---- S2: projections, transposed: C[proj_col][row] ----
    #pragma unroll
    for (int q = 0; q < 6; ++q) {
        int unit = wv * 6 + q;
        int c = unit >> 3, n = unit & 7;
        const float* bias; int ks, hg, wso;
        switch (c) {
            case 0:  bias = pv;  ks = 2; hg = 0;  wso = OFF_PV; break;
            case 1:  bias = pm;  ks = 2; hg = 8;  wso = OFF_PM; break;
            case 2:  bias = pi_; ks = 1; hg = 16; wso = OFF_PI; break;
            case 3:  bias = pb_; ks = 1; hg = 20; wso = OFF_PB; break;
            case 4:  bias = pc_; ks = 2; hg = 24; wso = OFF_PC; break;
            default: bias = pf_; ks = 4; hg = 32; wso = OFF_PF; break;
        }
        f32x4 acc = *(const f32x4*)&bias[n * 16 + lg * 4];
        int hrow = col & 7;
        for (int kk = 0; kk < ks; ++kk) {
            short8 A = *(const short8*)&ws[wso + (((n * ks + kk) * 64 + lane) << 3)];
            short8 B = *(const short8*)&s_h[(hrow * 48 + ((hg + kk * 4 + lg) ^ hrow)) << 3];
            acc = __builtin_amdgcn_mfma_f32_16x16x32_bf16(A, B, acc, 0, 0, 0);
        }
        if (col < 8) {
            int tok = c * 8 + col;
            int gt = n * 2 + (lg >> 1);
            uint2 w;
            w.x = cvt_pk_bf16(acc[0], acc[1]);
            w.y = cvt_pk_bf16(acc[2], acc[3]);
            *(uint2*)&s_tok[((tok * 16 + (gt ^ (tok & 15))) << 3) + (lg & 1) * 4] = w;
        }
    }
    __syncthreads();

    // ---- S3: QKV (MFMA; fragments preloaded). Q/K -> s_qk; V -> s_vt [*12] ----
    {
        for (int mt = 0; mt < 3; ++mt) {
            short8 A[4];
            int arow = mt * 16 + col;
            #pragma unroll
            for (int kk = 0; kk < 4; ++kk) {
                int g = kk * 4 + lg;
                A[kk] = *(const short8*)&s_tok[(arow * 16 + (g ^ (arow & 15))) << 3];
            }
            #pragma unroll
            for (int ni = 0; ni < 3; ++ni) {
                f32x4 acc = {qkvB_[ni], qkvB_[ni], qkvB_[ni], qkvB_[ni]};
                #pragma unroll
                for (int kk = 0; kk < 4; ++kk)
                    acc = __builtin_amdgcn_mfma_f32_16x16x32_bf16(A[kk], qkvBf[ni][kk], acc, 0, 0, 0);
                int cn = wv * 3 + ni;
                int cg = cn * 16 + col;                 // global qkv column
                if (cn < 16) {
                    // Q/K: col-major, token index XOR-swizzled by ((cg>>3)&3)<<2
                    int q4 = ((cg >> 3) & 3) << 2;
                    int tb = (mt * 16 + lg * 4) ^ q4;
                    uint2 w;
                    w.x = cvt_pk_bf16(acc[0], acc[1]);
                    w.y = cvt_pk_bf16(acc[2], acc[3]);
                    *(uint2*)&s_qk[cg * 48 + tb] = w;
                } else {
                    int d = cg - 256;
                    int h = d >> 5, ch = (d >> 4) & 1, nn = d & 15;
                    #pragma unroll
                    for (int r = 0; r < 4; ++r) {
                        int token = mt * 16 + lg * 4 + r;
                        int c2 = token >> 3, rb = token & 7;
                        int g2 = rb * 2 + (h >> 1);
                        int kidx = (h & 1) * 6 + c2;
                        s_vt[((g2 * 2 + ch) * 16 + nn) * 12 + kidx] = f2bf(acc[r]);
                    }
                }
            }
        }
    }
    __syncthreads();

    // ---- SCORES phase 1: MFMAs only (last readers of s_qk) ----
    f32x4 scf[2];
    {
        const int rb = wv;
        #pragma unroll
        for (int i = 0; i < 2; ++i) {
            const int hp = i;
            int p  = (col >= 6 && col < 12) ? 1 : 0;
            int qi = (col < 6) ? col : ((col < 12) ? col - 6 : 0);
            int tt = qi * 8 + rb;
            int h  = hp * 2 + p;
            int tsw = tt ^ (lg << 2);
            int abase = (h * 32 + lg * 8) * 48 + tsw;          // Q cols 0..127
            int bbase = (128 + h * 32 + lg * 8) * 48 + tsw;    // K cols 128..255
            short8 Aq, Bk;
            #pragma unroll
            for (int j = 0; j < 8; ++j) {
                Aq[j] = (short)s_qk[abase + j * 48];
                Bk[j] = (short)s_qk[bbase + j * 48];
            }
            f32x4 sc = {0.f, 0.f, 0.f, 0.f};
            scf[i] = __builtin_amdgcn_mfma_f32_16x16x32_bf16(Aq, Bk, sc, 0, 0, 0);
        }
    }
    __syncthreads();   // s_qk now dead -> its space becomes s_ctx + s_pp

    // ---- SCORES phase 2: max-free softmax in C-regs -> s_pp (wave-local) ----
    {
        #pragma unroll
        for (int i = 0; i < 2; ++i) {
            u16* pp = s_pp + (wv * 2 + i) * 256;
            f32x4 pr4;
            #pragma unroll
            for (int r = 0; r < 4; ++r) {
                int mr = lg * 4 + r;
                int prr = (mr >= 6 && mr < 12) ? 1 : 0;
                // softmax is shift-invariant; scores are O(1), clamp@60 guards overflow
                float v = fminf(scf[i][r] * 0.17677669529663687f, 60.f);
                bool inR = (col >= 6 * prr) && (col < 6 * prr + 6);
                float e = inR ? __expf(v) : 0.f;
                float s = e;
                #pragma unroll
                for (int off = 1; off < 16; off <<= 1)
                    s += __shfl_xor(s, off, 16);
                pr4[r] = (mr < 12) ? (e / s) : 0.f;
            }
            uint2 w;
            w.x = cvt_pk_bf16(pr4[0], pr4[1]);
            w.y = cvt_pk_bf16(pr4[2], pr4[3]);
            *(uint2*)&pp[col * 16 + lg * 4] = w;   // Ppad[k=col][m quad]
        }
    }
    // no barrier: s_pp is wave-local (same-wave DS ops are program-ordered;
    // s_vt/s_ctx overlay protected by the scores-P1 barrier)

    // ---- PV: ctx = P @ V via MFMA (A from s_pp block-diag, B 2x b64 from s_vt) ----
    {
        const int rb = wv;
        #pragma unroll
        for (int i = 0; i < 2; ++i) {
            const int hp = i;
            u16* pp = s_pp + (wv * 2 + i) * 256;
            short8 Ap;
            if (lg < 2) {
                #pragma unroll
                for (int j = 0; j < 8; ++j)
                    Ap[j] = (short)pp[(lg * 8 + j) * 16 + col];
            } else {
                #pragma unroll
                for (int j = 0; j < 8; ++j) Ap[j] = 0;
            }
            int g2 = rb * 2 + hp;
            #pragma unroll
            for (int ch = 0; ch < 2; ++ch) {
                // 12-wide rows: two 8B-aligned b64 reads; upper half's last 4 slots
                // (k=12..15) read the next row / region (finite) x pp rows 12..15 == 0.
                int vbase = ((g2 * 2 + ch) * 16 + col) * 12 + ((lg & 1) * 8);
                uint2 vlo = *(const uint2*)&s_vt[vbase];
                uint2 vhi = *(const uint2*)&s_vt[vbase + 4];
                union { uint4 u; short8 s; } cvu;
                cvu.u.x = vlo.x; cvu.u.y = vlo.y; cvu.u.z = vhi.x; cvu.u.w = vhi.y;
                short8 Bv = cvu.s;
                f32x4 c = {0.f, 0.f, 0.f, 0.f};
                c = __builtin_amdgcn_mfma_f32_16x16x32_bf16(Ap, Bv, c, 0, 0, 0);
                #pragma unroll
                for (int r = 0; r < 4; ++r) {
                    int mr = lg * 4 + r;
                    if (mr < 12) {
                        int pq = mr >= 6 ? 1 : 0;
                        int qi = mr - 6 * pq;
                        int token = qi * 8 + rb;
                        int d = (hp * 2 + pq) * 32 + ch * 16 + col;
                        s_ctx[((token * 16 + ((d >> 3) ^ (token & 15))) << 3) + (d & 7)] = f2bf(c[r]);
                    }
                }
            }
        }
    }
    __syncthreads();   // s_pp dead -> region becomes s_part

    // ---- S6 (8-wave): out-proj transposed + residual + LN w/ cross-wave partials ----
    {
        const int mo = wv;                     // this wave's 16 output cols
        short8 Afr[4];
        #pragma unroll
        for (int kk = 0; kk < 4; ++kk)
            Afr[kk] = *(const short8*)&ws[OFF_WO + (((mo * 4 + kk) * 64 + lane) << 3)];
        f32x4 biasv = *(const f32x4*)&bo[mo * 16 + lg * 4];
        f32x4 accs[3];
        #pragma unroll
        for (int tt = 0; tt < 3; ++tt) {
            int tokr = tt * 16 + col;
            f32x4 acc = biasv;
            #pragma unroll
            for (int kk = 0; kk < 4; ++kk) {
                short8 Bf = *(const short8*)&s_ctx[(tokr * 16 + ((kk * 4 + lg) ^ (tokr & 15))) << 3];
                acc = __builtin_amdgcn_mfma_f32_16x16x32_bf16(Afr[kk], Bf, acc, 0, 0, 0);
            }
            const u16* rp = &s_tok[((tokr * 16 + ((mo * 2 + (lg >> 1)) ^ (tokr & 15))) << 3) + (lg & 1) * 4];
            #pragma unroll
            for (int r = 0; r < 4; ++r) acc[r] += bf2f(rp[r]);
            accs[tt] = acc;
            float s1 = acc[0] + acc[1] + acc[2] + acc[3];
            float s2 = acc[0]*acc[0] + acc[1]*acc[1] + acc[2]*acc[2] + acc[3]*acc[3];
            s1 += __shfl_xor(s1, 16, 64); s1 += __shfl_xor(s1, 32, 64);
            s2 += __shfl_xor(s2, 16, 64); s2 += __shfl_xor(s2, 32, 64);
            if (lg == 0) {
                float2 pw; pw.x = s1; pw.y = s2;
                *(float2*)&s_part[(tokr * 8 + wv) * 2] = pw;
            }
        }
        __syncthreads();
        f32x4 gv = *(const f32x4*)&gg[mo * 16 + lg * 4];
        f32x4 bv = *(const f32x4*)&beta[mo * 16 + lg * 4];
        #pragma unroll
        for (int tt = 0; tt < 3; ++tt) {
            int tokr = tt * 16 + col;
            const float* pr = &s_part[tokr * 16];
            f32x4 p0 = *(const f32x4*)pr;
            f32x4 p1 = *(const f32x4*)(pr + 4);
            f32x4 p2 = *(const f32x4*)(pr + 8);
            f32x4 p3 = *(const f32x4*)(pr + 12);
            float S1 = p0[0]+p0[2]+p1[0]+p1[2]+p2[0]+p2[2]+p3[0]+p3[2];
            float S2 = p0[1]+p0[3]+p1[1]+p1[3]+p2[1]+p2[3]+p3[1]+p3[3];
            float mu = S1 * (1.f / 128.f);
            float var = S2 * (1.f / 128.f) - mu * mu;
            float rs = rsqrtf(var + LN_EPS);
            f32x4 a = accs[tt];
            uint2 w;
            w.x = cvt_pk_bf16((a[0]-mu)*rs*gv[0]+bv[0], (a[1]-mu)*rs*gv[1]+bv[1]);
            w.y = cvt_pk_bf16((a[2]-mu)*rs*gv[2]+bv[2], (a[3]-mu)*rs*gv[3]+bv[3]);
            *(uint2*)&s_tok[((tokr * 16 + ((mo * 2 + (lg >> 1)) ^ (tokr & 15))) << 3) + (lg & 1) * 4] = w;
        }
    }
    __syncthreads();

    // ---- S7: mean-pool over 6 tokens ----
    if (t < 128) {
        int row = t >> 4, gch = t & 15;
        float fa[8] = {0, 0, 0, 0, 0, 0, 0, 0};
        #pragma unroll
        for (int c = 0; c < 6; ++c) {
            int tok = c * 8 + row;
            short8 v = *(const short8*)&s_tok[(tok * 16 + (gch ^ (tok & 15))) << 3];
            #pragma unroll
            for (int j = 0; j < 8; ++j) fa[j] += bf2f((u16)v[j]);
        }
        short8 o;
        #pragma unroll
        for (int j = 0; j < 8; ++j) o[j] = (short)f2bf(fa[j] * (1.f / 6.f));
        *(short8*)&s_pool[(row * 16 + (gch ^ row)) << 3] = o;
    }
    __syncthreads();

    // ---- S8: pooled @ Wp + bp, ReLU -> direct coalesced global store ----
    {
        int arow = col & 7;
        short8 A[4];
        #pragma unroll
        for (int kk = 0; kk < 4; ++kk) {
            int g = kk * 4 + lg;
            A[kk] = *(const short8*)&s_pool[(arow * 16 + (g ^ arow)) << 3];
        }
        #pragma unroll
        for (int ni = 0; ni < 2; ++ni) {
            int n = wv * 2 + ni;
            float b = bp[n * 16 + col];
            f32x4 acc = {b, b, b, b};
            #pragma unroll
            for (int kk = 0; kk < 4; ++kk) {
                short8 Bf = *(const short8*)&ws[OFF_WP + (((n * 4 + kk) * 64 + lane) << 3)];
                acc = __builtin_amdgcn_mfma_f32_16x16x32_bf16(A[kk], Bf, acc, 0, 0, 0);
            }
            if (lg < 2) {
                // D[m=lg*4+r][n=col]: per (n,r), lanes 0-15 / 16-31 each cover one
                // contiguous 64B row segment -> coalesced without LDS staging.
                #pragma unroll
                for (int r = 0; r < 4; ++r) {
                    int row = lg * 4 + r;
                    out[((size_t)blk * 8 + row) * 256 + n * 16 + col] = fmaxf(acc[r], 0.f);
                }
            }
        }
    }
}

extern "C" void kernel_launch(void* const* d_in, const int* in_sizes, int n_in,
                              void* d_out, int out_size, void* d_ws, size_t ws_size,
                              hipStream_t stream) {
    const float* x    = (const float*)d_in[0];
    const float* Wv   = (const float*)d_in[1];
    const float* bv   = (const float*)d_in[2];
    const float* Wm   = (const float*)d_in[3];
    const float* bm   = (const float*)d_in[4];
    const float* Wi   = (const float*)d_in[5];
    const float* bi   = (const float*)d_in[6];
    const float* Wb   = (const float*)d_in[7];
    const float* bb   = (const float*)d_in[8];
    const float* Wc   = (const float*)d_in[9];
    const float* bc   = (const float*)d_in[10];
    const float* Wf   = (const float*)d_in[11];
    const float* bf_  = (const float*)d_in[12];
    const float* Pv   = (const float*)d_in[13];
    const float* pv   = (const float*)d_in[14];
    const float* Pm   = (const float*)d_in[15];
    const float* pm   = (const float*)d_in[16];
    const float* Pi   = (const float*)d_in[17];
    const float* pii  = (const float*)d_in[18];
    const float* Pb   = (const float*)d_in[19];
    const float* pb   = (const float*)d_in[20];
    const float* Pc   = (const float*)d_in[21];
    const float* pc   = (const float*)d_in[22];
    const float* Pf   = (const float*)d_in[23];
    const float* pf   = (const float*)d_in[24];
    const float* Wqkv = (const float*)d_in[25];
    const float* bqkv = (const float*)d_in[26];
    const float* Wo   = (const float*)d_in[27];
    const float* bo   = (const float*)d_in[28];
    const float* gg   = (const float*)d_in[29];
    const float* beta = (const float*)d_in[30];
    const float* Wp   = (const float*)d_in[31];
    const float* bp   = (const float*)d_in[32];
    float* out = (float*)d_out;
    u16* ws = (u16*)d_ws;

    convert_weights<<<(CW_TOTAL + 511) / 512, 512, 0, stream>>>(
        Wqkv, Wo, Wp, Pv, Pm, Pi, Pb, Pc, Pf,
        Wv, Wm, Wi, Wb, Wc, Wf, bv, bm, bi, bb, bc, bf_, ws);

    const int Bn = in_sizes[0] / 29;       // 65536
    asmlp_mfma<<<Bn / 8, 512, 0, stream>>>(
        x, pv, pm, pii, pb, pc, pf,
        bqkv, bo, gg, beta, bp, ws, out);
}